// Round 1
// baseline (522.337 us; speedup 1.0000x reference)
//
#include <hip/hip_runtime.h>
#include <cstdint>
#include <cstddef>

typedef __bf16          bf16x8  __attribute__((ext_vector_type(8)));
typedef float           f32x4   __attribute__((ext_vector_type(4)));
typedef unsigned short  u16x8   __attribute__((ext_vector_type(8)));

// fp32 -> bf16 with round-to-nearest-even. RNE is REQUIRED: truncation's
// coherent -0.2% bias compounds multiplicatively over 8 layers x 2048-term
// dots and would blow the 1.4e-4 absmax threshold.
__device__ __forceinline__ unsigned short f32_bf16_rne(float f) {
  union { float f; unsigned u; } v; v.f = f;
  unsigned u = v.u + 0x7FFFu + ((v.u >> 16) & 1u);
  return (unsigned short)(u >> 16);
}

// ---------------- flat fp32 -> bf16 convert (vectorized, G13) ----------------
__global__ void cvt_f32_bf16(const float* __restrict__ in,
                             unsigned short* __restrict__ out, int n8) {
  int idx = blockIdx.x * 256 + threadIdx.x;
  int stride = gridDim.x * 256;
  for (int i = idx; i < n8; i += stride) {
    float4 a = ((const float4*)in)[2 * (size_t)i];
    float4 b = ((const float4*)in)[2 * (size_t)i + 1];
    u16x8 o;
    o[0] = f32_bf16_rne(a.x); o[1] = f32_bf16_rne(a.y);
    o[2] = f32_bf16_rne(a.z); o[3] = f32_bf16_rne(a.w);
    o[4] = f32_bf16_rne(b.x); o[5] = f32_bf16_rne(b.y);
    o[6] = f32_bf16_rne(b.z); o[7] = f32_bf16_rne(b.w);
    *(u16x8*)(out + (size_t)i * 8) = o;
  }
}

// ------------- beta (H x O, f32) -> betaT (O x H, bf16) transpose ------------
__global__ void cvt_transpose(const float* __restrict__ in,
                              unsigned short* __restrict__ out, int H, int O) {
  __shared__ float tile[32][33];  // +1 pad: no bank conflicts
  int o0 = blockIdx.x * 32, h0 = blockIdx.y * 32;
  int tx = threadIdx.x & 31, ty = threadIdx.x >> 5;  // 256 thr: ty 0..7
  #pragma unroll
  for (int i = ty; i < 32; i += 8)
    tile[i][tx] = in[(size_t)(h0 + i) * O + (o0 + tx)];
  __syncthreads();
  #pragma unroll
  for (int i = ty; i < 32; i += 8)
    out[(size_t)(o0 + i) * H + (h0 + tx)] = f32_bf16_rne(tile[tx][i]);
}

// ---------------- 128x128-tile bf16 GEMM, B-transposed form ------------------
// C[m,n] = sum_k A[m,k] * B[n,k]   (A: MxK bf16, B: NxK bf16, row-major)
// m97 structure: BK=32, 4 waves (2x2), each wave 64x64 = 4x4 16x16 fragments,
// global_load_lds width 16 staging, 2-barrier K-loop.
// EPI=0: C = bf16( relu(acc*scale) ), ldc=N.  EPI=1: C = f32( acc*scale ).
template <int EPI>
__global__ __launch_bounds__(256)
void gemm_bt(const unsigned short* __restrict__ A,
             const unsigned short* __restrict__ B,
             void* __restrict__ C, int N, int K, float scale) {
  __shared__ __bf16 As[128 * 32] __attribute__((aligned(16)));
  __shared__ __bf16 Bs[128 * 32] __attribute__((aligned(16)));

  const int tid  = threadIdx.x;
  const int lane = tid & 63;
  const int wave = tid >> 6;
  const int wr   = wave >> 1, wc = wave & 1;
  const int l16  = lane & 15, kgrp = lane >> 4;

  const int brow0 = blockIdx.y * 128;
  const int bcol0 = blockIdx.x * 128;

  // --- staging addressing: tile is [128 rows][32 k] bf16, 64 B/row, 8 KiB.
  // Wave w covers bytes [w*2048, w*2048+2048) in two 1024 B gload_lds calls.
  // LDS dest is wave-uniform base + lane*16 (hardware adds the lane term).
  const int offb  = wave * 2048 + lane * 16;   // byte offset of chunk 0
  const int srow  = offb >> 6;                 // row within tile
  const int selem = (offb & 63) >> 1;          // k element within row
  const unsigned short* gA0 = A + (size_t)(brow0 + srow) * K + selem;
  const unsigned short* gA1 = A + (size_t)(brow0 + srow + 16) * K + selem;
  const unsigned short* gB0 = B + (size_t)(bcol0 + srow) * K + selem;
  const unsigned short* gB1 = B + (size_t)(bcol0 + srow + 16) * K + selem;
  __bf16* lA0 = &As[wave * 1024];          // 2048 B / 2 = 1024 elems per wave
  __bf16* lA1 = &As[wave * 1024 + 512];
  __bf16* lB0 = &Bs[wave * 1024];
  __bf16* lB1 = &Bs[wave * 1024 + 512];

  f32x4 acc[4][4] = {};

  // fragment read base: A row = wr*64 + m*16 + l16, k = kgrp*8 .. +8 (b128)
  const int aoff = (wr * 64 + l16) * 32 + kgrp * 8;
  const int boff = (wc * 64 + l16) * 32 + kgrp * 8;

  for (int k0 = 0; k0 < K; k0 += 32) {
    __builtin_amdgcn_global_load_lds(
        (const __attribute__((address_space(1))) void*)(gA0 + k0),
        (__attribute__((address_space(3))) void*)lA0, 16, 0, 0);
    __builtin_amdgcn_global_load_lds(
        (const __attribute__((address_space(1))) void*)(gA1 + k0),
        (__attribute__((address_space(3))) void*)lA1, 16, 0, 0);
    __builtin_amdgcn_global_load_lds(
        (const __attribute__((address_space(1))) void*)(gB0 + k0),
        (__attribute__((address_space(3))) void*)lB0, 16, 0, 0);
    __builtin_amdgcn_global_load_lds(
        (const __attribute__((address_space(1))) void*)(gB1 + k0),
        (__attribute__((address_space(3))) void*)lB1, 16, 0, 0);
    asm volatile("s_waitcnt vmcnt(0)" ::: "memory");
    __syncthreads();

    bf16x8 af[4], bfv[4];
    #pragma unroll
    for (int m = 0; m < 4; ++m)
      af[m] = *(const bf16x8*)(As + aoff + m * 16 * 32);
    #pragma unroll
    for (int n = 0; n < 4; ++n)
      bfv[n] = *(const bf16x8*)(Bs + boff + n * 16 * 32);
    #pragma unroll
    for (int m = 0; m < 4; ++m)
      #pragma unroll
      for (int n = 0; n < 4; ++n)
        acc[m][n] =
            __builtin_amdgcn_mfma_f32_16x16x32_bf16(af[m], bfv[n], acc[m][n], 0, 0, 0);
    __syncthreads();
  }

  // --- epilogue. D layout: col = lane&15, row = (lane>>4)*4 + reg (m89/m91).
  const int crow0 = brow0 + wr * 64 + kgrp * 4;
  const int ccol0 = bcol0 + wc * 64 + l16;
  if constexpr (EPI == 0) {
    unsigned short* Co = (unsigned short*)C;
    #pragma unroll
    for (int m = 0; m < 4; ++m)
      #pragma unroll
      for (int n = 0; n < 4; ++n)
        #pragma unroll
        for (int j = 0; j < 4; ++j) {
          float v = acc[m][n][j] * scale;
          v = v > 0.0f ? v : 0.0f;  // fused ReLU
          Co[(size_t)(crow0 + m * 16 + j) * N + (ccol0 + n * 16)] = f32_bf16_rne(v);
        }
  } else {
    float* Co = (float*)C;
    #pragma unroll
    for (int m = 0; m < 4; ++m)
      #pragma unroll
      for (int n = 0; n < 4; ++n)
        #pragma unroll
        for (int j = 0; j < 4; ++j)
          Co[(size_t)(crow0 + m * 16 + j) * N + (ccol0 + n * 16)] =
              acc[m][n][j] * scale;
  }
}

extern "C" void kernel_launch(void* const* d_in, const int* in_sizes, int n_in,
                              void* d_out, int out_size, void* d_ws, size_t ws_size,
                              hipStream_t stream) {
  const float* x    = (const float*)d_in[0];  // (4096, 2048)
  const float* W    = (const float*)d_in[1];  // (8, 2048, 2048)
  const float* beta = (const float*)d_in[2];  // (2048, 1024)
  float* out = (float*)d_out;                 // (4096, 1024) f32

  const int Bn = 4096, H = 2048, L = 8, O = 1024;

  // workspace layout (bf16 as ushort): y0 | y1 | Wb | betaT  = 46.1 MB
  unsigned short* y0    = (unsigned short*)d_ws;
  unsigned short* y1    = y0 + (size_t)Bn * H;
  unsigned short* Wb    = y1 + (size_t)Bn * H;
  unsigned short* betaT = Wb + (size_t)H * H;

  // x -> bf16
  {
    int n8 = Bn * H / 8;
    int grid = (n8 + 255) / 256;
    if (grid > 2048) grid = 2048;
    cvt_f32_bf16<<<grid, 256, 0, stream>>>(x, y0, n8);
  }
  // beta -> betaT bf16 (transposed so readout uses the same BT GEMM)
  cvt_transpose<<<dim3(O / 32, H / 32), 256, 0, stream>>>(beta, betaT, H, O);

  const float s1 = 0.02209708691207961f;  // 1/sqrt(2048)
  unsigned short* yin = y0;
  unsigned short* yout = y1;
  for (int l = 0; l < L; ++l) {
    int n8 = H * H / 8;
    int grid = (n8 + 255) / 256;
    if (grid > 2048) grid = 2048;
    cvt_f32_bf16<<<grid, 256, 0, stream>>>(W + (size_t)l * H * H, Wb, n8);
    gemm_bt<0><<<dim3(H / 128, Bn / 128), 256, 0, stream>>>(yin, Wb, yout, H, H, s1);
    unsigned short* t = yin; yin = yout; yout = t;
  }
  // readout: out = y @ betaT^T / 2048, fp32
  gemm_bt<1><<<dim3(O / 128, Bn / 128), 256, 0, stream>>>(yin, betaT, out, O, H,
                                                          1.0f / 2048.0f);
}

// Round 2
// 428.924 us; speedup vs baseline: 1.2178x; 1.2178x over previous
//
#include <hip/hip_runtime.h>
#include <cstdint>
#include <cstddef>

typedef __bf16          bf16x8  __attribute__((ext_vector_type(8)));
typedef float           f32x4   __attribute__((ext_vector_type(4)));
typedef unsigned short  u16x8   __attribute__((ext_vector_type(8)));

__device__ __forceinline__ unsigned short f32_bf16_rne(float f) {
  union { float f; unsigned u; } v; v.f = f;
  unsigned u = v.u + 0x7FFFu + ((v.u >> 16) & 1u);
  return (unsigned short)(u >> 16);
}

// ---------------- flat fp32 -> bf16 convert (vectorized, G13) ----------------
__global__ void cvt_f32_bf16(const float* __restrict__ in,
                             unsigned short* __restrict__ out, int n8) {
  int idx = blockIdx.x * 256 + threadIdx.x;
  int stride = gridDim.x * 256;
  for (int i = idx; i < n8; i += stride) {
    float4 a = ((const float4*)in)[2 * (size_t)i];
    float4 b = ((const float4*)in)[2 * (size_t)i + 1];
    u16x8 o;
    o[0] = f32_bf16_rne(a.x); o[1] = f32_bf16_rne(a.y);
    o[2] = f32_bf16_rne(a.z); o[3] = f32_bf16_rne(a.w);
    o[4] = f32_bf16_rne(b.x); o[5] = f32_bf16_rne(b.y);
    o[6] = f32_bf16_rne(b.z); o[7] = f32_bf16_rne(b.w);
    *(u16x8*)(out + (size_t)i * 8) = o;
  }
}

// ------------- beta (H x O, f32) -> betaT (O x H, bf16) transpose ------------
__global__ void cvt_transpose(const float* __restrict__ in,
                              unsigned short* __restrict__ out, int H, int O) {
  __shared__ float tile[32][33];
  int o0 = blockIdx.x * 32, h0 = blockIdx.y * 32;
  int tx = threadIdx.x & 31, ty = threadIdx.x >> 5;
  #pragma unroll
  for (int i = ty; i < 32; i += 8)
    tile[i][tx] = in[(size_t)(h0 + i) * O + (o0 + tx)];
  __syncthreads();
  #pragma unroll
  for (int i = ty; i < 32; i += 8)
    out[(size_t)(o0 + i) * H + (h0 + tx)] = f32_bf16_rne(tile[tx][i]);
}

// ======================= 256x128 8-wave pipelined GEMM =======================
// C[m,n] = relu(scale * sum_k A[m,k]*B[n,k]) -> bf16.   A: MxK, B: NxK bf16.
// T2: XOR swizzle byte^=((row&7)<<4) on 128-B LDS rows (linear gload_lds dest,
//     inverse-swizzled per-lane global src, swizzled ds_read  — rule 21).
// T3/T4: 3-deep K-tile pipeline, counted vmcnt(6) once per K-tile, never 0 in
//     steady state. Raw s_barrier (no __syncthreads vmcnt(0) drain).
// T5: setprio(1) around each 16-MFMA cluster.
// T1: XCD-chunked block swizzle (grid 256 = 8 XCDs x 32 blocks, row-chunked).

#define GLOAD(gp, lp)                                                   \
  __builtin_amdgcn_global_load_lds(                                     \
      (const __attribute__((address_space(1))) void*)(gp),              \
      (__attribute__((address_space(3))) void*)(lp), 16, 0, 0)

#define MFMA16 __builtin_amdgcn_mfma_f32_16x16x32_bf16

#define PHASE(MH, STAGE)                                                      \
  do {                                                                        \
    bf16x8 a00 = *(const bf16x8*)(cA + aBase + ((MH)*2+0)*1024 + c0);         \
    bf16x8 a01 = *(const bf16x8*)(cA + aBase + ((MH)*2+0)*1024 + c1);         \
    bf16x8 a10 = *(const bf16x8*)(cA + aBase + ((MH)*2+1)*1024 + c0);         \
    bf16x8 a11 = *(const bf16x8*)(cA + aBase + ((MH)*2+1)*1024 + c1);         \
    bf16x8 b00 = *(const bf16x8*)(cB + bBase + 0*1024 + c0);                  \
    bf16x8 b01 = *(const bf16x8*)(cB + bBase + 0*1024 + c1);                  \
    bf16x8 b10 = *(const bf16x8*)(cB + bBase + 1*1024 + c0);                  \
    bf16x8 b11 = *(const bf16x8*)(cB + bBase + 1*1024 + c1);                  \
    bf16x8 b20 = *(const bf16x8*)(cB + bBase + 2*1024 + c0);                  \
    bf16x8 b21 = *(const bf16x8*)(cB + bBase + 2*1024 + c1);                  \
    bf16x8 b30 = *(const bf16x8*)(cB + bBase + 3*1024 + c0);                  \
    bf16x8 b31 = *(const bf16x8*)(cB + bBase + 3*1024 + c1);                  \
    STAGE                                                                     \
    __builtin_amdgcn_sched_barrier(0);                                        \
    __builtin_amdgcn_s_barrier();                                             \
    asm volatile("s_waitcnt lgkmcnt(0)" ::: "memory");                        \
    __builtin_amdgcn_sched_barrier(0);                                        \
    __builtin_amdgcn_s_setprio(1);                                            \
    acc[(MH)*2+0][0] = MFMA16(a00, b00, acc[(MH)*2+0][0], 0, 0, 0);           \
    acc[(MH)*2+0][1] = MFMA16(a00, b10, acc[(MH)*2+0][1], 0, 0, 0);           \
    acc[(MH)*2+0][2] = MFMA16(a00, b20, acc[(MH)*2+0][2], 0, 0, 0);           \
    acc[(MH)*2+0][3] = MFMA16(a00, b30, acc[(MH)*2+0][3], 0, 0, 0);           \
    acc[(MH)*2+1][0] = MFMA16(a10, b00, acc[(MH)*2+1][0], 0, 0, 0);           \
    acc[(MH)*2+1][1] = MFMA16(a10, b10, acc[(MH)*2+1][1], 0, 0, 0);           \
    acc[(MH)*2+1][2] = MFMA16(a10, b20, acc[(MH)*2+1][2], 0, 0, 0);           \
    acc[(MH)*2+1][3] = MFMA16(a10, b30, acc[(MH)*2+1][3], 0, 0, 0);           \
    acc[(MH)*2+0][0] = MFMA16(a01, b01, acc[(MH)*2+0][0], 0, 0, 0);           \
    acc[(MH)*2+0][1] = MFMA16(a01, b11, acc[(MH)*2+0][1], 0, 0, 0);           \
    acc[(MH)*2+0][2] = MFMA16(a01, b21, acc[(MH)*2+0][2], 0, 0, 0);           \
    acc[(MH)*2+0][3] = MFMA16(a01, b31, acc[(MH)*2+0][3], 0, 0, 0);           \
    acc[(MH)*2+1][0] = MFMA16(a11, b01, acc[(MH)*2+1][0], 0, 0, 0);           \
    acc[(MH)*2+1][1] = MFMA16(a11, b11, acc[(MH)*2+1][1], 0, 0, 0);           \
    acc[(MH)*2+1][2] = MFMA16(a11, b21, acc[(MH)*2+1][2], 0, 0, 0);           \
    acc[(MH)*2+1][3] = MFMA16(a11, b31, acc[(MH)*2+1][3], 0, 0, 0);           \
    __builtin_amdgcn_s_setprio(0);                                            \
    __builtin_amdgcn_sched_barrier(0);                                        \
    __builtin_amdgcn_s_barrier();                                             \
  } while (0)

__global__ __launch_bounds__(512, 2)
void gemm256x128(const unsigned short* __restrict__ A,
                 const unsigned short* __restrict__ B,
                 unsigned short* __restrict__ Cp, int N, int K, float scale) {
  // 3-deep K-tile pipeline: A slots 256x64 bf16 (32 KiB), B slots 128x64.
  __shared__ __bf16 As[3 * 256 * 64] __attribute__((aligned(16)));  // 96 KiB
  __shared__ __bf16 Bs[3 * 128 * 64] __attribute__((aligned(16)));  // 48 KiB

  const int tid  = threadIdx.x;
  const int lane = tid & 63;
  const int wave = tid >> 6;      // 0..7
  const int wr   = wave >> 1;     // 0..3 (M)
  const int wc   = wave & 1;      // 0..1 (N)
  const int l16  = lane & 15;
  const int kgrp = lane >> 4;     // 0..3

  // T1: XCD-chunked swizzle (nwg=256, 32 blocks/XCD, chunks = 2 grid rows)
  const int p   = blockIdx.y * gridDim.x + blockIdx.x;
  const int lin = (p & 7) * (256 >> 3) + (p >> 3);
  const int brow0 = (lin >> 4) * 256;   // gridDim.x == 16
  const int bcol0 = (lin & 15) * 128;

  // ---- ds_read addressing (swizzled): elem = row*64 + (col ^ ((row&7)<<3))
  const int xorv  = (l16 & 7) << 3;
  const int c0    = (kgrp * 8) ^ xorv;
  const int c1    = (32 + kgrp * 8) ^ xorv;
  const int aBase = (wr * 64 + l16) * 64;
  const int bBase = (wc * 64 + l16) * 64;

  // ---- staging: per g-block of 64 rows, thread covers 8 elems (16 B).
  // Linear LDS offset L = g*4096 + tid*8 elems; row = g*64 + tid/8;
  // global col pre-swizzled so that swizzled ds_read sees logical data.
  const int srow = tid >> 3;                              // 0..63
  const int scol = ((tid & 7) * 8) ^ ((srow & 7) << 3);   // elements
  const unsigned short* gA0 = A + (size_t)(brow0 +   0 + srow) * K + scol;
  const unsigned short* gA1 = A + (size_t)(brow0 +  64 + srow) * K + scol;
  const unsigned short* gA2 = A + (size_t)(brow0 + 128 + srow) * K + scol;
  const unsigned short* gA3 = A + (size_t)(brow0 + 192 + srow) * K + scol;
  const unsigned short* gB0 = B + (size_t)(bcol0 +   0 + srow) * K + scol;
  const unsigned short* gB1 = B + (size_t)(bcol0 +  64 + srow) * K + scol;

  f32x4 acc[4][4] = {};

  const int NT = K >> 6;  // 64-wide K-tiles

  // ---- prologue: stage K-tiles 0 and 1 (6 gloads each), keep 6 in flight
  {
    GLOAD(gA0, &As[0 * 4096 + tid * 8]);
    GLOAD(gA1, &As[1 * 4096 + tid * 8]);
    GLOAD(gA2, &As[2 * 4096 + tid * 8]);
    GLOAD(gA3, &As[3 * 4096 + tid * 8]);
    GLOAD(gB0, &Bs[0 * 4096 + tid * 8]);
    GLOAD(gB1, &Bs[1 * 4096 + tid * 8]);
    GLOAD(gA0 + 64, &As[16384 + 0 * 4096 + tid * 8]);
    GLOAD(gA1 + 64, &As[16384 + 1 * 4096 + tid * 8]);
    GLOAD(gA2 + 64, &As[16384 + 2 * 4096 + tid * 8]);
    GLOAD(gA3 + 64, &As[16384 + 3 * 4096 + tid * 8]);
    GLOAD(gB0 + 64, &Bs[8192 + 0 * 4096 + tid * 8]);
    GLOAD(gB1 + 64, &Bs[8192 + 1 * 4096 + tid * 8]);
    asm volatile("s_waitcnt vmcnt(6)" ::: "memory");
    __builtin_amdgcn_s_barrier();
  }

  int s = 0;  // K-tile t occupies slot t%3
  for (int t = 0; t < NT; ++t) {
    const __bf16* cA = &As[s * 16384];
    const __bf16* cB = &Bs[s * 8192];
    int su = s + 2; if (su >= 3) su -= 3;
    __bf16* dA = &As[su * 16384];
    __bf16* dB = &Bs[su * 8192];
    const bool stg = (t < NT - 2);
    const size_t ko = (size_t)(t + 2) * 64;

    PHASE(0,
      if (stg) {
        GLOAD(gA0 + ko, dA + 0 * 4096 + tid * 8);
        GLOAD(gA1 + ko, dA + 1 * 4096 + tid * 8);
        GLOAD(gA2 + ko, dA + 2 * 4096 + tid * 8);
      }
    );
    PHASE(1,
      if (stg) {
        GLOAD(gA3 + ko, dA + 3 * 4096 + tid * 8);
        GLOAD(gB0 + ko, dB + 0 * 4096 + tid * 8);
        GLOAD(gB1 + ko, dB + 1 * 4096 + tid * 8);
        asm volatile("s_waitcnt vmcnt(6)" ::: "memory");
      } else if (t == NT - 2) {
        asm volatile("s_waitcnt vmcnt(0)" ::: "memory");
      }
    );
    s = s + 1; if (s == 3) s = 0;
  }

  // ---- epilogue: relu(acc*scale) -> bf16. D: col=lane&15, row=(lane>>4)*4+j
  const int crow0 = brow0 + wr * 64 + kgrp * 4;
  const int ccol0 = bcol0 + wc * 64 + l16;
  #pragma unroll
  for (int m = 0; m < 4; ++m)
    #pragma unroll
    for (int n = 0; n < 4; ++n)
      #pragma unroll
      for (int j = 0; j < 4; ++j) {
        float v = acc[m][n][j] * scale;
        v = v > 0.0f ? v : 0.0f;
        Cp[(size_t)(crow0 + m * 16 + j) * N + (ccol0 + n * 16)] = f32_bf16_rne(v);
      }
}

// ---------------- 128x128 m97-structure GEMM (readout only) ------------------
__global__ __launch_bounds__(256)
void gemm_bt_f32(const unsigned short* __restrict__ A,
                 const unsigned short* __restrict__ B,
                 float* __restrict__ C, int N, int K, float scale) {
  __shared__ __bf16 As[128 * 32] __attribute__((aligned(16)));
  __shared__ __bf16 Bs[128 * 32] __attribute__((aligned(16)));

  const int tid  = threadIdx.x;
  const int lane = tid & 63;
  const int wave = tid >> 6;
  const int wr   = wave >> 1, wc = wave & 1;
  const int l16  = lane & 15, kgrp = lane >> 4;

  const int brow0 = blockIdx.y * 128;
  const int bcol0 = blockIdx.x * 128;

  const int offb  = wave * 2048 + lane * 16;
  const int srow  = offb >> 6;
  const int selem = (offb & 63) >> 1;
  const unsigned short* gA0 = A + (size_t)(brow0 + srow) * K + selem;
  const unsigned short* gA1 = A + (size_t)(brow0 + srow + 16) * K + selem;
  const unsigned short* gB0 = B + (size_t)(bcol0 + srow) * K + selem;
  const unsigned short* gB1 = B + (size_t)(bcol0 + srow + 16) * K + selem;
  __bf16* lA0 = &As[wave * 1024];
  __bf16* lA1 = &As[wave * 1024 + 512];
  __bf16* lB0 = &Bs[wave * 1024];
  __bf16* lB1 = &Bs[wave * 1024 + 512];

  f32x4 acc[4][4] = {};
  const int aoff = (wr * 64 + l16) * 32 + kgrp * 8;
  const int boff = (wc * 64 + l16) * 32 + kgrp * 8;

  for (int k0 = 0; k0 < K; k0 += 32) {
    GLOAD(gA0 + k0, lA0);
    GLOAD(gA1 + k0, lA1);
    GLOAD(gB0 + k0, lB0);
    GLOAD(gB1 + k0, lB1);
    asm volatile("s_waitcnt vmcnt(0)" ::: "memory");
    __syncthreads();

    bf16x8 af[4], bfv[4];
    #pragma unroll
    for (int m = 0; m < 4; ++m)
      af[m] = *(const bf16x8*)(As + aoff + m * 16 * 32);
    #pragma unroll
    for (int n = 0; n < 4; ++n)
      bfv[n] = *(const bf16x8*)(Bs + boff + n * 16 * 32);
    #pragma unroll
    for (int m = 0; m < 4; ++m)
      #pragma unroll
      for (int n = 0; n < 4; ++n)
        acc[m][n] = MFMA16(af[m], bfv[n], acc[m][n], 0, 0, 0);
    __syncthreads();
  }

  const int crow0 = brow0 + wr * 64 + kgrp * 4;
  const int ccol0 = bcol0 + wc * 64 + l16;
  #pragma unroll
  for (int m = 0; m < 4; ++m)
    #pragma unroll
    for (int n = 0; n < 4; ++n)
      #pragma unroll
      for (int j = 0; j < 4; ++j)
        C[(size_t)(crow0 + m * 16 + j) * N + (ccol0 + n * 16)] =
            acc[m][n][j] * scale;
}

extern "C" void kernel_launch(void* const* d_in, const int* in_sizes, int n_in,
                              void* d_out, int out_size, void* d_ws, size_t ws_size,
                              hipStream_t stream) {
  const float* x    = (const float*)d_in[0];  // (4096, 2048)
  const float* W    = (const float*)d_in[1];  // (8, 2048, 2048)
  const float* beta = (const float*)d_in[2];  // (2048, 1024)
  float* out = (float*)d_out;                 // (4096, 1024) f32

  const int Bn = 4096, H = 2048, L = 8, O = 1024;

  unsigned short* y0    = (unsigned short*)d_ws;
  unsigned short* y1    = y0 + (size_t)Bn * H;
  unsigned short* Wb    = y1 + (size_t)Bn * H;
  unsigned short* betaT = Wb + (size_t)H * H;

  {
    int n8 = Bn * H / 8;
    int grid = (n8 + 255) / 256;
    if (grid > 2048) grid = 2048;
    cvt_f32_bf16<<<grid, 256, 0, stream>>>(x, y0, n8);
  }
  cvt_transpose<<<dim3(O / 32, H / 32), 256, 0, stream>>>(beta, betaT, H, O);

  const float s1 = 0.02209708691207961f;  // 1/sqrt(2048)
  unsigned short* yin = y0;
  unsigned short* yout = y1;
  for (int l = 0; l < L; ++l) {
    int n8 = H * H / 8;
    int grid = (n8 + 255) / 256;
    if (grid > 2048) grid = 2048;
    cvt_f32_bf16<<<grid, 256, 0, stream>>>(W + (size_t)l * H * H, Wb, n8);
    gemm256x128<<<dim3(H / 128, Bn / 256), 512, 0, stream>>>(yin, Wb, yout, H, H, s1);
    unsigned short* t = yin; yin = yout; yout = t;
  }
  gemm_bt_f32<<<dim3(O / 128, Bn / 128), 256, 0, stream>>>(yin, betaT, out, O, H,
                                                           1.0f / 2048.0f);
}

// Round 3
// 408.512 us; speedup vs baseline: 1.2786x; 1.0500x over previous
//
#include <hip/hip_runtime.h>
#include <cstdint>
#include <cstddef>

typedef __bf16          bf16x8  __attribute__((ext_vector_type(8)));
typedef float           f32x4   __attribute__((ext_vector_type(4)));
typedef unsigned short  u16x8   __attribute__((ext_vector_type(8)));

__device__ __forceinline__ unsigned short f32_bf16_rne(float f) {
  union { float f; unsigned u; } v; v.f = f;
  unsigned u = v.u + 0x7FFFu + ((v.u >> 16) & 1u);
  return (unsigned short)(u >> 16);
}

// ---------------- flat fp32 -> bf16 convert (vectorized, G13) ----------------
__global__ void cvt_f32_bf16(const float* __restrict__ in,
                             unsigned short* __restrict__ out, int n8) {
  int idx = blockIdx.x * 256 + threadIdx.x;
  int stride = gridDim.x * 256;
  for (int i = idx; i < n8; i += stride) {
    float4 a = ((const float4*)in)[2 * (size_t)i];
    float4 b = ((const float4*)in)[2 * (size_t)i + 1];
    u16x8 o;
    o[0] = f32_bf16_rne(a.x); o[1] = f32_bf16_rne(a.y);
    o[2] = f32_bf16_rne(a.z); o[3] = f32_bf16_rne(a.w);
    o[4] = f32_bf16_rne(b.x); o[5] = f32_bf16_rne(b.y);
    o[6] = f32_bf16_rne(b.z); o[7] = f32_bf16_rne(b.w);
    *(u16x8*)(out + (size_t)i * 8) = o;
  }
}

// ------------- beta (H x O, f32) -> betaT (O x H, bf16) transpose ------------
__global__ void cvt_transpose(const float* __restrict__ in,
                              unsigned short* __restrict__ out, int H, int O) {
  __shared__ float tile[32][33];
  int o0 = blockIdx.x * 32, h0 = blockIdx.y * 32;
  int tx = threadIdx.x & 31, ty = threadIdx.x >> 5;
  #pragma unroll
  for (int i = ty; i < 32; i += 8)
    tile[i][tx] = in[(size_t)(h0 + i) * O + (o0 + tx)];
  __syncthreads();
  #pragma unroll
  for (int i = ty; i < 32; i += 8)
    out[(size_t)(o0 + i) * H + (h0 + tx)] = f32_bf16_rne(tile[tx][i]);
}

#define GLOAD(gp, lp)                                                   \
  __builtin_amdgcn_global_load_lds(                                     \
      (const __attribute__((address_space(1))) void*)(gp),              \
      (__attribute__((address_space(3))) void*)(lp), 16, 0, 0)

#define MFMA16 __builtin_amdgcn_mfma_f32_16x16x32_bf16

// ======================= 128x256 8-wave pipelined GEMM =======================
// C[m,n] = relu(scale * sum_k A[m,k]*B[n,k]) -> bf16.   A: MxK, B: NxK bf16.
// Waves 2M x 4N, per-wave 64x64. Phases split along K: each phase reads its
// 4 A-frags + 4 B-frags ONCE (8 ds_read_b128) and does 16 MFMA -> 16 reads :
// 32 MFMA per K-tile (0.031 LDS-B/FLOP, was 0.047 in the 256x128 shape).
// T2 swizzle both-sides; T3/T4 3-deep pipeline with counted vmcnt(6);
// T5 setprio; T1 free via gridDim.x == 8 == #XCDs (B-panel per XCD L2).

#define PHASE(KK, STAGE)                                                      \
  do {                                                                        \
    const int c = cc##KK;                                                     \
    bf16x8 a0 = *(const bf16x8*)(cA + aBase + 0 * 1024 + c);                  \
    bf16x8 a1 = *(const bf16x8*)(cA + aBase + 1 * 1024 + c);                  \
    bf16x8 a2 = *(const bf16x8*)(cA + aBase + 2 * 1024 + c);                  \
    bf16x8 a3 = *(const bf16x8*)(cA + aBase + 3 * 1024 + c);                  \
    bf16x8 b0 = *(const bf16x8*)(cB + bBase + 0 * 1024 + c);                  \
    bf16x8 b1 = *(const bf16x8*)(cB + bBase + 1 * 1024 + c);                  \
    bf16x8 b2 = *(const bf16x8*)(cB + bBase + 2 * 1024 + c);                  \
    bf16x8 b3 = *(const bf16x8*)(cB + bBase + 3 * 1024 + c);                  \
    STAGE                                                                     \
    __builtin_amdgcn_sched_barrier(0);                                        \
    __builtin_amdgcn_s_barrier();                                             \
    asm volatile("s_waitcnt lgkmcnt(0)" ::: "memory");                        \
    __builtin_amdgcn_sched_barrier(0);                                        \
    __builtin_amdgcn_s_setprio(1);                                            \
    acc[0][0] = MFMA16(a0, b0, acc[0][0], 0, 0, 0);                           \
    acc[0][1] = MFMA16(a0, b1, acc[0][1], 0, 0, 0);                           \
    acc[0][2] = MFMA16(a0, b2, acc[0][2], 0, 0, 0);                           \
    acc[0][3] = MFMA16(a0, b3, acc[0][3], 0, 0, 0);                           \
    acc[1][0] = MFMA16(a1, b0, acc[1][0], 0, 0, 0);                           \
    acc[1][1] = MFMA16(a1, b1, acc[1][1], 0, 0, 0);                           \
    acc[1][2] = MFMA16(a1, b2, acc[1][2], 0, 0, 0);                           \
    acc[1][3] = MFMA16(a1, b3, acc[1][3], 0, 0, 0);                           \
    acc[2][0] = MFMA16(a2, b0, acc[2][0], 0, 0, 0);                           \
    acc[2][1] = MFMA16(a2, b1, acc[2][1], 0, 0, 0);                           \
    acc[2][2] = MFMA16(a2, b2, acc[2][2], 0, 0, 0);                           \
    acc[2][3] = MFMA16(a2, b3, acc[2][3], 0, 0, 0);                           \
    acc[3][0] = MFMA16(a3, b0, acc[3][0], 0, 0, 0);                           \
    acc[3][1] = MFMA16(a3, b1, acc[3][1], 0, 0, 0);                           \
    acc[3][2] = MFMA16(a3, b2, acc[3][2], 0, 0, 0);                           \
    acc[3][3] = MFMA16(a3, b3, acc[3][3], 0, 0, 0);                           \
    __builtin_amdgcn_s_setprio(0);                                            \
    __builtin_amdgcn_sched_barrier(0);                                        \
    __builtin_amdgcn_s_barrier();                                             \
  } while (0)

__global__ __launch_bounds__(512, 2)
void gemm128x256(const unsigned short* __restrict__ A,
                 const unsigned short* __restrict__ B,
                 unsigned short* __restrict__ Cp, int N, int K, float scale) {
  __shared__ __bf16 As[3 * 128 * 64] __attribute__((aligned(16)));  // 48 KiB
  __shared__ __bf16 Bs[3 * 256 * 64] __attribute__((aligned(16)));  // 96 KiB

  const int tid  = threadIdx.x;
  const int lane = tid & 63;
  const int wave = tid >> 6;      // 0..7
  const int wr   = wave >> 2;     // 0..1 (M)
  const int wc   = wave & 3;      // 0..3 (N)
  const int l16  = lane & 15;
  const int kgrp = lane >> 4;     // 0..3

  // gridDim.x = 8 = #XCDs: dispatch round-robin pins B-panel (bcol) per XCD.
  const int brow0 = blockIdx.y * 128;
  const int bcol0 = blockIdx.x * 256;

  // ds_read addressing (swizzled): elem = row*64 + (col ^ ((row&7)<<3))
  const int xorv  = (l16 & 7) << 3;
  const int cc0   = (kgrp * 8) ^ xorv;
  const int cc1   = (32 + kgrp * 8) ^ xorv;
  const int aBase = (wr * 64 + l16) * 64;
  const int bBase = (wc * 64 + l16) * 64;

  // staging: each GLOAD line = 64 rows x 64 elems (8 KB), thread covers 16 B.
  const int srow = tid >> 3;                              // 0..63
  const int scol = ((tid & 7) * 8) ^ ((srow & 7) << 3);   // pre-swizzled col
  const unsigned short* gA0 = A + (size_t)(brow0 +   0 + srow) * K + scol;
  const unsigned short* gA1 = A + (size_t)(brow0 +  64 + srow) * K + scol;
  const unsigned short* gB0 = B + (size_t)(bcol0 +   0 + srow) * K + scol;
  const unsigned short* gB1 = B + (size_t)(bcol0 +  64 + srow) * K + scol;
  const unsigned short* gB2 = B + (size_t)(bcol0 + 128 + srow) * K + scol;
  const unsigned short* gB3 = B + (size_t)(bcol0 + 192 + srow) * K + scol;

  f32x4 acc[4][4] = {};

  const int NT = K >> 6;  // 64-wide K-tiles

  // prologue: stage K-tiles 0 and 1 (6 gloads each), keep 6 in flight
  {
    GLOAD(gA0, &As[0 * 4096 + tid * 8]);
    GLOAD(gA1, &As[1 * 4096 + tid * 8]);
    GLOAD(gB0, &Bs[0 * 4096 + tid * 8]);
    GLOAD(gB1, &Bs[1 * 4096 + tid * 8]);
    GLOAD(gB2, &Bs[2 * 4096 + tid * 8]);
    GLOAD(gB3, &Bs[3 * 4096 + tid * 8]);
    GLOAD(gA0 + 64, &As[8192 + 0 * 4096 + tid * 8]);
    GLOAD(gA1 + 64, &As[8192 + 1 * 4096 + tid * 8]);
    GLOAD(gB0 + 64, &Bs[16384 + 0 * 4096 + tid * 8]);
    GLOAD(gB1 + 64, &Bs[16384 + 1 * 4096 + tid * 8]);
    GLOAD(gB2 + 64, &Bs[16384 + 2 * 4096 + tid * 8]);
    GLOAD(gB3 + 64, &Bs[16384 + 3 * 4096 + tid * 8]);
    asm volatile("s_waitcnt vmcnt(6)" ::: "memory");
    __builtin_amdgcn_s_barrier();
  }

  int s = 0;  // K-tile t occupies slot t%3
  for (int t = 0; t < NT; ++t) {
    const __bf16* cA = &As[s * 8192];
    const __bf16* cB = &Bs[s * 16384];
    int su = s + 2; if (su >= 3) su -= 3;
    __bf16* dA = &As[su * 8192];
    __bf16* dB = &Bs[su * 16384];
    const bool stg = (t < NT - 2);
    const size_t ko = (size_t)(t + 2) * 64;

    PHASE(0,
      if (stg) {
        GLOAD(gA0 + ko, dA + 0 * 4096 + tid * 8);
        GLOAD(gA1 + ko, dA + 1 * 4096 + tid * 8);
        GLOAD(gB0 + ko, dB + 0 * 4096 + tid * 8);
      }
    );
    PHASE(1,
      if (stg) {
        GLOAD(gB1 + ko, dB + 1 * 4096 + tid * 8);
        GLOAD(gB2 + ko, dB + 2 * 4096 + tid * 8);
        GLOAD(gB3 + ko, dB + 3 * 4096 + tid * 8);
        asm volatile("s_waitcnt vmcnt(6)" ::: "memory");
      } else if (t == NT - 2) {
        asm volatile("s_waitcnt vmcnt(0)" ::: "memory");
      }
    );
    s = s + 1; if (s == 3) s = 0;
  }

  // epilogue: relu(acc*scale) -> bf16. D: col=lane&15, row=(lane>>4)*4+j
  const int crow0 = brow0 + wr * 64 + kgrp * 4;
  const int ccol0 = bcol0 + wc * 64 + l16;
  #pragma unroll
  for (int m = 0; m < 4; ++m)
    #pragma unroll
    for (int n = 0; n < 4; ++n)
      #pragma unroll
      for (int j = 0; j < 4; ++j) {
        float v = acc[m][n][j] * scale;
        v = v > 0.0f ? v : 0.0f;
        Cp[(size_t)(crow0 + m * 16 + j) * N + (ccol0 + n * 16)] = f32_bf16_rne(v);
      }
}

// ---------------- 128x128 m97-structure GEMM (readout only) ------------------
__global__ __launch_bounds__(256)
void gemm_bt_f32(const unsigned short* __restrict__ A,
                 const unsigned short* __restrict__ B,
                 float* __restrict__ C, int N, int K, float scale) {
  __shared__ __bf16 As[128 * 32] __attribute__((aligned(16)));
  __shared__ __bf16 Bs[128 * 32] __attribute__((aligned(16)));

  const int tid  = threadIdx.x;
  const int lane = tid & 63;
  const int wave = tid >> 6;
  const int wr   = wave >> 1, wc = wave & 1;
  const int l16  = lane & 15, kgrp = lane >> 4;

  const int brow0 = blockIdx.y * 128;
  const int bcol0 = blockIdx.x * 128;

  const int offb  = wave * 2048 + lane * 16;
  const int srow  = offb >> 6;
  const int selem = (offb & 63) >> 1;
  const unsigned short* gA0 = A + (size_t)(brow0 + srow) * K + selem;
  const unsigned short* gA1 = A + (size_t)(brow0 + srow + 16) * K + selem;
  const unsigned short* gB0 = B + (size_t)(bcol0 + srow) * K + selem;
  const unsigned short* gB1 = B + (size_t)(bcol0 + srow + 16) * K + selem;
  __bf16* lA0 = &As[wave * 1024];
  __bf16* lA1 = &As[wave * 1024 + 512];
  __bf16* lB0 = &Bs[wave * 1024];
  __bf16* lB1 = &Bs[wave * 1024 + 512];

  f32x4 acc[4][4] = {};
  const int aoff = (wr * 64 + l16) * 32 + kgrp * 8;
  const int boff = (wc * 64 + l16) * 32 + kgrp * 8;

  for (int k0 = 0; k0 < K; k0 += 32) {
    GLOAD(gA0 + k0, lA0);
    GLOAD(gA1 + k0, lA1);
    GLOAD(gB0 + k0, lB0);
    GLOAD(gB1 + k0, lB1);
    asm volatile("s_waitcnt vmcnt(0)" ::: "memory");
    __syncthreads();

    bf16x8 af[4], bfv[4];
    #pragma unroll
    for (int m = 0; m < 4; ++m)
      af[m] = *(const bf16x8*)(As + aoff + m * 16 * 32);
    #pragma unroll
    for (int n = 0; n < 4; ++n)
      bfv[n] = *(const bf16x8*)(Bs + boff + n * 16 * 32);
    #pragma unroll
    for (int m = 0; m < 4; ++m)
      #pragma unroll
      for (int n = 0; n < 4; ++n)
        acc[m][n] = MFMA16(af[m], bfv[n], acc[m][n], 0, 0, 0);
    __syncthreads();
  }

  const int crow0 = brow0 + wr * 64 + kgrp * 4;
  const int ccol0 = bcol0 + wc * 64 + l16;
  #pragma unroll
  for (int m = 0; m < 4; ++m)
    #pragma unroll
    for (int n = 0; n < 4; ++n)
      #pragma unroll
      for (int j = 0; j < 4; ++j)
        C[(size_t)(crow0 + m * 16 + j) * N + (ccol0 + n * 16)] =
            acc[m][n][j] * scale;
}

extern "C" void kernel_launch(void* const* d_in, const int* in_sizes, int n_in,
                              void* d_out, int out_size, void* d_ws, size_t ws_size,
                              hipStream_t stream) {
  const float* x    = (const float*)d_in[0];  // (4096, 2048)
  const float* W    = (const float*)d_in[1];  // (8, 2048, 2048)
  const float* beta = (const float*)d_in[2];  // (2048, 1024)
  float* out = (float*)d_out;                 // (4096, 1024) f32

  const int Bn = 4096, H = 2048, L = 8, O = 1024;

  unsigned short* y0    = (unsigned short*)d_ws;
  unsigned short* y1    = y0 + (size_t)Bn * H;
  unsigned short* Wb    = y1 + (size_t)Bn * H;
  unsigned short* betaT = Wb + (size_t)H * H;

  {
    int n8 = Bn * H / 8;
    int grid = (n8 + 255) / 256;
    if (grid > 2048) grid = 2048;
    cvt_f32_bf16<<<grid, 256, 0, stream>>>(x, y0, n8);
  }
  cvt_transpose<<<dim3(O / 32, H / 32), 256, 0, stream>>>(beta, betaT, H, O);

  const float s1 = 0.02209708691207961f;  // 1/sqrt(2048)
  unsigned short* yin = y0;
  unsigned short* yout = y1;
  for (int l = 0; l < L; ++l) {
    int n8 = H * H / 8;
    int grid = (n8 + 255) / 256;
    if (grid > 2048) grid = 2048;
    cvt_f32_bf16<<<grid, 256, 0, stream>>>(W + (size_t)l * H * H, Wb, n8);
    gemm128x256<<<dim3(H / 256, Bn / 128), 512, 0, stream>>>(yin, Wb, yout, H, H, s1);
    unsigned short* t = yin; yin = yout; yout = t;
  }
  gemm_bt_f32<<<dim3(O / 128, Bn / 128), 256, 0, stream>>>(yin, betaT, out, O, H,
                                                           1.0f / 2048.0f);
}

// Round 4
// 404.558 us; speedup vs baseline: 1.2911x; 1.0098x over previous
//
#include <hip/hip_runtime.h>
#include <cstdint>
#include <cstddef>

typedef __bf16          bf16x8  __attribute__((ext_vector_type(8)));
typedef float           f32x4   __attribute__((ext_vector_type(4)));
typedef unsigned short  u16x8   __attribute__((ext_vector_type(8)));

__device__ __forceinline__ unsigned short f32_bf16_rne(float f) {
  union { float f; unsigned u; } v; v.f = f;
  unsigned u = v.u + 0x7FFFu + ((v.u >> 16) & 1u);
  return (unsigned short)(u >> 16);
}

// ---------------- flat fp32 -> bf16 convert (vectorized, G13) ----------------
__global__ void cvt_f32_bf16(const float* __restrict__ in,
                             unsigned short* __restrict__ out, int n8) {
  int idx = blockIdx.x * 256 + threadIdx.x;
  int stride = gridDim.x * 256;
  for (int i = idx; i < n8; i += stride) {
    float4 a = ((const float4*)in)[2 * (size_t)i];
    float4 b = ((const float4*)in)[2 * (size_t)i + 1];
    u16x8 o;
    o[0] = f32_bf16_rne(a.x); o[1] = f32_bf16_rne(a.y);
    o[2] = f32_bf16_rne(a.z); o[3] = f32_bf16_rne(a.w);
    o[4] = f32_bf16_rne(b.x); o[5] = f32_bf16_rne(b.y);
    o[6] = f32_bf16_rne(b.z); o[7] = f32_bf16_rne(b.w);
    *(u16x8*)(out + (size_t)i * 8) = o;
  }
}

// ------------- beta (H x O, f32) -> betaT (O x H, bf16) transpose ------------
__global__ void cvt_transpose(const float* __restrict__ in,
                              unsigned short* __restrict__ out, int H, int O) {
  __shared__ float tile[32][33];
  int o0 = blockIdx.x * 32, h0 = blockIdx.y * 32;
  int tx = threadIdx.x & 31, ty = threadIdx.x >> 5;
  #pragma unroll
  for (int i = ty; i < 32; i += 8)
    tile[i][tx] = in[(size_t)(h0 + i) * O + (o0 + tx)];
  __syncthreads();
  #pragma unroll
  for (int i = ty; i < 32; i += 8)
    out[(size_t)(o0 + i) * H + (h0 + tx)] = f32_bf16_rne(tile[tx][i]);
}

#define GLOAD(gp, lp)                                                   \
  __builtin_amdgcn_global_load_lds(                                     \
      (const __attribute__((address_space(1))) void*)(gp),              \
      (__attribute__((address_space(3))) void*)(lp), 16, 0, 0)

#define MFMA16 __builtin_amdgcn_mfma_f32_16x16x32_bf16

__device__ __forceinline__ void read_frags(bf16x8 (&fa)[2][4], bf16x8 (&fb)[2][4],
                                           const __bf16* sa, const __bf16* sb,
                                           int aBase, int bBase, int cc0, int cc1) {
  #pragma unroll
  for (int kk = 0; kk < 2; ++kk) {
    const int c = kk ? cc1 : cc0;
    #pragma unroll
    for (int m = 0; m < 4; ++m)
      fa[kk][m] = *(const bf16x8*)(sa + aBase + m * 1024 + c);
    #pragma unroll
    for (int n = 0; n < 4; ++n)
      fb[kk][n] = *(const bf16x8*)(sb + bBase + n * 1024 + c);
  }
}

__device__ __forceinline__ void mfma32(f32x4 (&acc)[4][4],
                                       const bf16x8 (&fa)[2][4],
                                       const bf16x8 (&fb)[2][4]) {
  #pragma unroll
  for (int kk = 0; kk < 2; ++kk)
    #pragma unroll
    for (int m = 0; m < 4; ++m)
      #pragma unroll
      for (int n = 0; n < 4; ++n)
        acc[m][n] = MFMA16(fa[kk][m], fb[kk][n], acc[m][n], 0, 0, 0);
}

// ================ 128x256 8-wave register-pipelined GEMM =====================
// C[m,n] = relu(scale * sum_k A[m,k]*B[n,k]) -> bf16.   A: MxK, B: NxK bf16.
// ONE barrier per K-tile; fragment regs double-buffered so the ds_read latency
// of K-tile t+1 drains UNDER the 32-MFMA burst of K-tile t (their lgkm wait is
// deferred to the next body's pre-barrier lgkm(0), by then free).
// Hazards: RAW  = vmcnt(6)+barrier before reads of slot t+1;
//          WAR  = pre-barrier lgkm(0) guarantees every wave's reads of a slot
//                 complete before the barrier that precedes its overwrite
//                 (3-deep slot rotation gives the 2-barrier separation).
// T1: gridDim.x == 8 == #XCDs pins each 1MB B-panel to one XCD's L2.
// T2: st-style XOR swizzle, both-sides (pre-swizzled global src + swz ds_read).

#define BODY(T, FA_C, FB_C, FA_N, FB_N)                                   \
  do {                                                                    \
    const int t_ = (T);                                                   \
    if (t_ + 2 < NT) {                                                    \
      const size_t ko = (size_t)(t_ + 2) * 64;                            \
      __bf16* dA = As + sst * 8192;                                       \
      __bf16* dB = Bs + sst * 16384;                                      \
      GLOAD(gA0 + ko, dA + 0 * 4096 + tid * 8);                           \
      GLOAD(gA1 + ko, dA + 1 * 4096 + tid * 8);                           \
      GLOAD(gB0 + ko, dB + 0 * 4096 + tid * 8);                           \
      GLOAD(gB1 + ko, dB + 1 * 4096 + tid * 8);                           \
      GLOAD(gB2 + ko, dB + 2 * 4096 + tid * 8);                           \
      GLOAD(gB3 + ko, dB + 3 * 4096 + tid * 8);                           \
      asm volatile("s_waitcnt lgkmcnt(0)" ::: "memory");                  \
      asm volatile("s_waitcnt vmcnt(6)" ::: "memory");                    \
    } else {                                                              \
      asm volatile("s_waitcnt lgkmcnt(0)" ::: "memory");                  \
      asm volatile("s_waitcnt vmcnt(0)" ::: "memory");                    \
    }                                                                     \
    __builtin_amdgcn_s_barrier();                                         \
    __builtin_amdgcn_sched_barrier(0);                                    \
    if (t_ + 1 < NT)                                                      \
      read_frags(FA_N, FB_N, As + srd * 8192, Bs + srd * 16384,           \
                 aBase, bBase, cc0, cc1);                                 \
    __builtin_amdgcn_s_setprio(1);                                        \
    mfma32(acc, FA_C, FB_C);                                              \
    __builtin_amdgcn_s_setprio(0);                                        \
    sst = sst + 1; if (sst == 3) sst = 0;                                 \
    srd = srd + 1; if (srd == 3) srd = 0;                                 \
  } while (0)

__global__ __launch_bounds__(512, 2)
void gemm128x256p(const unsigned short* __restrict__ A,
                  const unsigned short* __restrict__ B,
                  unsigned short* __restrict__ Cp, int N, int K, float scale) {
  __shared__ __bf16 As[3 * 128 * 64] __attribute__((aligned(16)));  // 48 KiB
  __shared__ __bf16 Bs[3 * 256 * 64] __attribute__((aligned(16)));  // 96 KiB

  const int tid  = threadIdx.x;
  const int lane = tid & 63;
  const int wave = tid >> 6;      // 0..7
  const int wr   = wave >> 2;     // 0..1 (M)
  const int wc   = wave & 3;      // 0..3 (N)
  const int l16  = lane & 15;
  const int kgrp = lane >> 4;     // 0..3

  const int brow0 = blockIdx.y * 128;
  const int bcol0 = blockIdx.x * 256;   // gridDim.x = 8 = #XCDs

  // ds_read addressing (swizzled): elem = row*64 + (col ^ ((row&7)<<3))
  const int xorv  = (l16 & 7) << 3;
  const int cc0   = (kgrp * 8) ^ xorv;
  const int cc1   = (32 + kgrp * 8) ^ xorv;
  const int aBase = (wr * 64 + l16) * 64;
  const int bBase = (wc * 64 + l16) * 64;

  // staging: each GLOAD line = 64 rows x 64 elems (8 KB), thread covers 16 B.
  const int srow = tid >> 3;                              // 0..63
  const int scol = ((tid & 7) * 8) ^ ((srow & 7) << 3);   // pre-swizzled col
  const unsigned short* gA0 = A + (size_t)(brow0 +   0 + srow) * K + scol;
  const unsigned short* gA1 = A + (size_t)(brow0 +  64 + srow) * K + scol;
  const unsigned short* gB0 = B + (size_t)(bcol0 +   0 + srow) * K + scol;
  const unsigned short* gB1 = B + (size_t)(bcol0 +  64 + srow) * K + scol;
  const unsigned short* gB2 = B + (size_t)(bcol0 + 128 + srow) * K + scol;
  const unsigned short* gB3 = B + (size_t)(bcol0 + 192 + srow) * K + scol;

  f32x4  acc[4][4] = {};
  bf16x8 fa0[2][4], fb0[2][4], fa1[2][4], fb1[2][4];

  const int NT = K >> 6;  // 64-wide K-tiles (K % 128 == 0 assumed)

  // prologue: stage slots 0 and 1; slot0 guaranteed, read its frags into buf0
  {
    GLOAD(gA0, &As[0 * 4096 + tid * 8]);
    GLOAD(gA1, &As[1 * 4096 + tid * 8]);
    GLOAD(gB0, &Bs[0 * 4096 + tid * 8]);
    GLOAD(gB1, &Bs[1 * 4096 + tid * 8]);
    GLOAD(gB2, &Bs[2 * 4096 + tid * 8]);
    GLOAD(gB3, &Bs[3 * 4096 + tid * 8]);
    GLOAD(gA0 + 64, &As[8192 + 0 * 4096 + tid * 8]);
    GLOAD(gA1 + 64, &As[8192 + 1 * 4096 + tid * 8]);
    GLOAD(gB0 + 64, &Bs[16384 + 0 * 4096 + tid * 8]);
    GLOAD(gB1 + 64, &Bs[16384 + 1 * 4096 + tid * 8]);
    GLOAD(gB2 + 64, &Bs[16384 + 2 * 4096 + tid * 8]);
    GLOAD(gB3 + 64, &Bs[16384 + 3 * 4096 + tid * 8]);
    asm volatile("s_waitcnt vmcnt(6)" ::: "memory");
    __builtin_amdgcn_s_barrier();
    read_frags(fa0, fb0, As, Bs, aBase, bBase, cc0, cc1);
  }

  int sst = 2, srd = 1;
  for (int t = 0; t < NT; t += 2) {
    BODY(t,     fa0, fb0, fa1, fb1);
    BODY(t + 1, fa1, fb1, fa0, fb0);
  }

  // epilogue: relu(acc*scale) -> bf16. D: col=lane&15, row=(lane>>4)*4+j
  const int crow0 = brow0 + wr * 64 + kgrp * 4;
  const int ccol0 = bcol0 + wc * 64 + l16;
  #pragma unroll
  for (int m = 0; m < 4; ++m)
    #pragma unroll
    for (int n = 0; n < 4; ++n)
      #pragma unroll
      for (int j = 0; j < 4; ++j) {
        float v = acc[m][n][j] * scale;
        v = v > 0.0f ? v : 0.0f;
        Cp[(size_t)(crow0 + m * 16 + j) * N + (ccol0 + n * 16)] = f32_bf16_rne(v);
      }
}

// ---------------- 128x128 m97-structure GEMM (readout only) ------------------
__global__ __launch_bounds__(256)
void gemm_bt_f32(const unsigned short* __restrict__ A,
                 const unsigned short* __restrict__ B,
                 float* __restrict__ C, int N, int K, float scale) {
  __shared__ __bf16 As[128 * 32] __attribute__((aligned(16)));
  __shared__ __bf16 Bs[128 * 32] __attribute__((aligned(16)));

  const int tid  = threadIdx.x;
  const int lane = tid & 63;
  const int wave = tid >> 6;
  const int wr   = wave >> 1, wc = wave & 1;
  const int l16  = lane & 15, kgrp = lane >> 4;

  const int brow0 = blockIdx.y * 128;
  const int bcol0 = blockIdx.x * 128;

  const int offb  = wave * 2048 + lane * 16;
  const int srow  = offb >> 6;
  const int selem = (offb & 63) >> 1;
  const unsigned short* gA0 = A + (size_t)(brow0 + srow) * K + selem;
  const unsigned short* gA1 = A + (size_t)(brow0 + srow + 16) * K + selem;
  const unsigned short* gB0 = B + (size_t)(bcol0 + srow) * K + selem;
  const unsigned short* gB1 = B + (size_t)(bcol0 + srow + 16) * K + selem;
  __bf16* lA0 = &As[wave * 1024];
  __bf16* lA1 = &As[wave * 1024 + 512];
  __bf16* lB0 = &Bs[wave * 1024];
  __bf16* lB1 = &Bs[wave * 1024 + 512];

  f32x4 acc[4][4] = {};
  const int aoff = (wr * 64 + l16) * 32 + kgrp * 8;
  const int boff = (wc * 64 + l16) * 32 + kgrp * 8;

  for (int k0 = 0; k0 < K; k0 += 32) {
    GLOAD(gA0 + k0, lA0);
    GLOAD(gA1 + k0, lA1);
    GLOAD(gB0 + k0, lB0);
    GLOAD(gB1 + k0, lB1);
    asm volatile("s_waitcnt vmcnt(0)" ::: "memory");
    __syncthreads();

    bf16x8 af[4], bfv[4];
    #pragma unroll
    for (int m = 0; m < 4; ++m)
      af[m] = *(const bf16x8*)(As + aoff + m * 16 * 32);
    #pragma unroll
    for (int n = 0; n < 4; ++n)
      bfv[n] = *(const bf16x8*)(Bs + boff + n * 16 * 32);
    #pragma unroll
    for (int m = 0; m < 4; ++m)
      #pragma unroll
      for (int n = 0; n < 4; ++n)
        acc[m][n] = MFMA16(af[m], bfv[n], acc[m][n], 0, 0, 0);
    __syncthreads();
  }

  const int crow0 = brow0 + wr * 64 + kgrp * 4;
  const int ccol0 = bcol0 + wc * 64 + l16;
  #pragma unroll
  for (int m = 0; m < 4; ++m)
    #pragma unroll
    for (int n = 0; n < 4; ++n)
      #pragma unroll
      for (int j = 0; j < 4; ++j)
        C[(size_t)(crow0 + m * 16 + j) * N + (ccol0 + n * 16)] =
            acc[m][n][j] * scale;
}

extern "C" void kernel_launch(void* const* d_in, const int* in_sizes, int n_in,
                              void* d_out, int out_size, void* d_ws, size_t ws_size,
                              hipStream_t stream) {
  const float* x    = (const float*)d_in[0];  // (4096, 2048)
  const float* W    = (const float*)d_in[1];  // (8, 2048, 2048)
  const float* beta = (const float*)d_in[2];  // (2048, 1024)
  float* out = (float*)d_out;                 // (4096, 1024) f32

  const int Bn = 4096, H = 2048, L = 8, O = 1024;

  // ws layout (bf16 as ushort): y0 | y1 | Wb[8 layers] | betaT  = 105 MB
  unsigned short* y0    = (unsigned short*)d_ws;
  unsigned short* y1    = y0 + (size_t)Bn * H;
  unsigned short* Wb    = y1 + (size_t)Bn * H;
  unsigned short* betaT = Wb + (size_t)L * H * H;

  // all 8 W layers -> bf16 in ONE kernel (201 MB traffic, one launch)
  {
    int n8 = L * H * H / 8;
    cvt_f32_bf16<<<2048, 256, 0, stream>>>(W, Wb, n8);
  }
  // x -> bf16
  {
    int n8 = Bn * H / 8;
    int grid = (n8 + 255) / 256;
    if (grid > 2048) grid = 2048;
    cvt_f32_bf16<<<grid, 256, 0, stream>>>(x, y0, n8);
  }
  cvt_transpose<<<dim3(O / 32, H / 32), 256, 0, stream>>>(beta, betaT, H, O);

  const float s1 = 0.02209708691207961f;  // 1/sqrt(2048)
  unsigned short* yin = y0;
  unsigned short* yout = y1;
  for (int l = 0; l < L; ++l) {
    gemm128x256p<<<dim3(H / 256, Bn / 128), 512, 0, stream>>>(
        yin, Wb + (size_t)l * H * H, yout, H, H, s1);
    unsigned short* t = yin; yin = yout; yout = t;
  }
  gemm_bt_f32<<<dim3(O / 128, Bn / 128), 256, 0, stream>>>(yin, betaT, out, O, H,
                                                           1.0f / 2048.0f);
}